// Round 1
// baseline (176.551 us; speedup 1.0000x reference)
//
#include <hip/hip_runtime.h>
#include <cstddef>

// Problem: B=8, Cin=32, D=16, H=W=32 -> ConvTranspose3d(32->64, k=3, s=2, p=1)
// -> mean over depth (D'=31) -> +bias -> softmax over 64 channels -> tanh*2.
// Output: (8, 64, 1, 63, 63) fp32.
//
// Key reduction: mean over depth folds into weights =>
//   A0 = sum_d x - x[d=0]   (pairs with kd=0)
//   A1 = sum_d x            (pairs with kd=1)
//   A2 = sum_d x - x[d=15]  (pairs with kd=2)
//   sum_d y = sum_kd Tconv2d(A_kd, w[:,:,kd,:,:]),   m = cb + (1/31)*sum_d y
// Parity classes of (oh, ow): even->1 tap (k=1), odd->2 taps (k=0 at (o+1)/2,
// k=2 at (o-1)/2). No H/W boundary clipping for valid outputs.

namespace {
constexpr int PLANE  = 8 * 32 * 32 * 32;        // 262144 floats per A plane
constexpr int OFF_EE = 0;                        // T=3
constexpr int OFF_EO = 32 * 64 * 3;              // 6144,  T=6
constexpr int OFF_OE = OFF_EO + 32 * 64 * 6;     // 18432, T=6
constexpr int OFF_OO = OFF_OE + 32 * 64 * 6;     // 30720, T=12
constexpr int OFF_CB = OFF_OO + 32 * 64 * 12;    // 55296, cb[64]
constexpr int OFF_A  = OFF_CB + 64;              // 55360, then 3 planes
// total ws floats = 55360 + 3*262144 = 841792 (~3.4 MB)
}

// ---------------- weight transform + fused bias ----------------
extern "C" __global__ void k_transform(const float* __restrict__ w,
                                       const float* __restrict__ conv_bias,
                                       const float* __restrict__ bias,
                                       float* __restrict__ ws) {
  int t = blockIdx.x * 256 + threadIdx.x;       // 2048 threads = cin*64+cout
  if (t < 64) ws[OFF_CB + t] = conv_bias[t] + bias[t];
  if (t >= 32 * 64) return;
  const float s = 1.0f / 31.0f;
  const float* src = w + t * 27;                // w[cin][cout][kd][kh][kw]
  float wv[27];
#pragma unroll
  for (int i = 0; i < 27; ++i) wv[i] = src[i] * s;

  float* dee = ws + OFF_EE + t * 3;
  float* deo = ws + OFF_EO + t * 6;
  float* doe = ws + OFF_OE + t * 6;
  float* doo = ws + OFF_OO + t * 12;
#pragma unroll
  for (int kd = 0; kd < 3; ++kd) {
    dee[kd] = wv[kd * 9 + 4];                   // kh=1, kw=1
    deo[kd * 2 + 0] = wv[kd * 9 + 3 + 0];       // kh=1, kw=0 (iw=cc+1)
    deo[kd * 2 + 1] = wv[kd * 9 + 3 + 2];       // kh=1, kw=2 (iw=cc)
    doe[kd * 2 + 0] = wv[kd * 9 + 0 + 1];       // kh=0 (ih=(oh+1)/2), kw=1
    doe[kd * 2 + 1] = wv[kd * 9 + 6 + 1];       // kh=2 (ih=(oh-1)/2), kw=1
    doo[kd * 4 + 0] = wv[kd * 9 + 0];           // (kh=0,kw=0)
    doo[kd * 4 + 1] = wv[kd * 9 + 2];           // (kh=0,kw=2)
    doo[kd * 4 + 2] = wv[kd * 9 + 6];           // (kh=2,kw=0)
    doo[kd * 4 + 3] = wv[kd * 9 + 8];           // (kh=2,kw=2)
  }
}

// ---------------- depth reduce: x -> A0, A1, A2 ----------------
extern "C" __global__ void k_reduce(const float* __restrict__ x,
                                    float* __restrict__ ws) {
  int t = blockIdx.x * 256 + threadIdx.x;       // 262144 threads
  int bc = t >> 10;                             // b*32+cin
  const float* xp = x + (size_t)bc * 16384 + (t & 1023);
  float x0 = xp[0];
  float sum = x0;
#pragma unroll
  for (int d = 1; d < 15; ++d) sum += xp[d * 1024];
  float x15 = xp[15 * 1024];
  sum += x15;
  float* Ap = ws + OFF_A;
  Ap[t] = sum - x0;
  Ap[PLANE + t] = sum;
  Ap[2 * PLANE + t] = sum - x15;
}

// ---------------- main: 2D tconv taps + softmax + tanh ----------------
template <int NH, int NW>
__device__ __forceinline__ void accum_f(const float* __restrict__ A,
                                        const float* __restrict__ wt,
                                        int b, int cin0, int ih0, int ih1,
                                        int iw0, int iw1, float acc[64]) {
  constexpr int T = 3 * NH * NW;
  for (int ci = 0; ci < 8; ++ci) {
    const int cin = cin0 + ci;
    const float* ap = A + (size_t)(b * 32 + cin) * 1024;
    float av[T];
#pragma unroll
    for (int kd = 0; kd < 3; ++kd) {
#pragma unroll
      for (int hi = 0; hi < NH; ++hi) {
        int ih = hi ? ih1 : ih0;
#pragma unroll
        for (int wi = 0; wi < NW; ++wi) {
          int iw = wi ? iw1 : iw0;
          av[(kd * NH + hi) * NW + wi] = ap[kd * PLANE + ih * 32 + iw];
        }
      }
    }
    const float* wr = wt + (size_t)cin * 64 * T;  // uniform -> s_load
#pragma unroll
    for (int co = 0; co < 64; ++co) {
#pragma unroll
      for (int tt = 0; tt < T; ++tt)
        acc[co] = fmaf(wr[co * T + tt], av[tt], acc[co]);
    }
  }
}

extern "C" __global__ __launch_bounds__(256) void k_main(
    const float* __restrict__ ws, float* __restrict__ out) {
  const int bid = blockIdx.x;                   // 512 blocks
  const int b  = bid >> 6;
  const int r  = bid & 63;
  const int rp = (r >> 5) & 1;                  // row parity
  const int k  = (r >> 1) & 15;                 // row-pair id
  const int cp = r & 1;                         // col parity
  const int tid = threadIdx.x;
  const int wq = __builtin_amdgcn_readfirstlane(tid >> 6);  // cin quarter
  const int lane = tid & 63;
  const int rr = lane >> 5, cc = lane & 31;
  const int oh = 4 * k + rp + 2 * rr;
  const int ow = 2 * cc + cp;
  const bool valid = (oh < 63) && (ow < 63);

  int ih0, ih1 = 0, iw0, iw1 = 0;
  if (rp) { int ia = (oh + 1) >> 1; ih0 = ia > 31 ? 31 : ia; ih1 = (oh - 1) >> 1; }
  else    { ih0 = oh >> 1; }
  if (cp) { int ja = cc + 1; iw0 = ja > 31 ? 31 : ja; iw1 = cc; }
  else    { iw0 = cc; }

  float acc[64];
#pragma unroll
  for (int i = 0; i < 64; ++i) acc[i] = 0.0f;

  const float* A = ws + OFF_A;
  const int cin0 = wq * 8;
  const int par = rp * 2 + cp;
  if      (par == 0) accum_f<1, 1>(A, ws + OFF_EE, b, cin0, ih0, ih1, iw0, iw1, acc);
  else if (par == 1) accum_f<1, 2>(A, ws + OFF_EO, b, cin0, ih0, ih1, iw0, iw1, acc);
  else if (par == 2) accum_f<2, 1>(A, ws + OFF_OE, b, cin0, ih0, ih1, iw0, iw1, acc);
  else               accum_f<2, 2>(A, ws + OFF_OO, b, cin0, ih0, ih1, iw0, iw1, acc);

  // cin-split reduce: waves 1..3 dump partials, wave 0 combines + epilogue.
  __shared__ float lds[3 * 64 * 65];            // 49.9 KB, stride 65 = conflict-free
  if (wq != 0) {
    float* row = &lds[((wq - 1) * 64 + lane) * 65];
#pragma unroll
    for (int c = 0; c < 64; ++c) row[c] = acc[c];
  }
  __syncthreads();
  if (wq != 0) return;

  const float* cb = ws + OFF_CB;
  float mx = -3.0e38f;
#pragma unroll
  for (int c = 0; c < 64; ++c) {
    acc[c] += lds[(0 * 64 + lane) * 65 + c] + lds[(1 * 64 + lane) * 65 + c] +
              lds[(2 * 64 + lane) * 65 + c] + cb[c];
    mx = fmaxf(mx, acc[c]);
  }
  float sum = 0.0f;
#pragma unroll
  for (int c = 0; c < 64; ++c) {
    float e = __expf(acc[c] - mx);
    acc[c] = e;
    sum += e;
  }
  const float rs = 1.0f / sum;
  if (valid) {
    float* op = out + (size_t)b * 64 * 3969 + (size_t)oh * 63 + ow;
#pragma unroll
    for (int c = 0; c < 64; ++c) {
      float s = acc[c] * rs;
      float e2 = __expf(2.0f * s);              // 2*tanh(s) = 2 - 4/(e^{2s}+1)
      op[(size_t)c * 3969] = 2.0f - 4.0f / (e2 + 1.0f);
    }
  }
}

extern "C" void kernel_launch(void* const* d_in, const int* in_sizes, int n_in,
                              void* d_out, int out_size, void* d_ws,
                              size_t ws_size, hipStream_t stream) {
  const float* x  = (const float*)d_in[0];
  const float* w  = (const float*)d_in[1];
  const float* cb = (const float*)d_in[2];
  const float* bs = (const float*)d_in[3];
  float* ws  = (float*)d_ws;
  float* out = (float*)d_out;

  hipLaunchKernelGGL(k_transform, dim3(8),    dim3(256), 0, stream, w, cb, bs, ws);
  hipLaunchKernelGGL(k_reduce,    dim3(1024), dim3(256), 0, stream, x, ws);
  hipLaunchKernelGGL(k_main,      dim3(512),  dim3(256), 0, stream, ws, out);
}

// Round 2
// 110.189 us; speedup vs baseline: 1.6022x; 1.6022x over previous
//
#include <hip/hip_runtime.h>
#include <cstddef>

// B=8, Cin=32, D=16, H=W=32 -> ConvTranspose3d(32->64, k=3, s=2, p=1)
// -> mean over depth (D'=31) -> +bias -> softmax over C=64 -> tanh*2.
// Output (8, 64, 1, 63, 63) fp32.
//
// Mean over depth folds into weights:
//   A0 = sum_d x - x[0]  (kd=0), A1 = sum_d x (kd=1), A2 = sum_d x - x[15] (kd=2)
//   m = cb + (1/31) * sum_kd Tconv2d(A_kd, w[:,:,kd])
// Parity classes of (oh,ow): even coord -> 1 tap, odd -> 2 taps. No H/W clip.
//
// k_main layout: 512 blocks x 512 threads (8 waves).
//   wave = cinq(4) x ch(2): each wave does 8 cins for one cout-half (32 accs).
//   ch is wave-uniform so weights stay scalar (s_load) operands of v_fmac.
//   Cross-wave cin reduce via LDS; softmax halves exchanged via tiny LDS.

namespace {
constexpr int PLANE  = 8 * 32 * 32 * 32;         // 262144 floats per A plane
constexpr int OFF_EE = 0;                         // T=3
constexpr int OFF_EO = 32 * 64 * 3;               // T=6
constexpr int OFF_OE = OFF_EO + 32 * 64 * 6;      // T=6
constexpr int OFF_OO = OFF_OE + 32 * 64 * 6;      // T=12
constexpr int OFF_CB = OFF_OO + 32 * 64 * 12;     // cb[64]
constexpr int OFF_A  = OFF_CB + 64;               // 3 planes follow
}

// ---------------- prep: weight transform (+bias) AND depth reduce ----------
extern "C" __global__ __launch_bounds__(256) void k_prep(
    const float* __restrict__ x, const float* __restrict__ w,
    const float* __restrict__ conv_bias, const float* __restrict__ bias,
    float* __restrict__ ws) {
  const int bid = blockIdx.x;
  const int tid = threadIdx.x;
  if (bid < 8) {
    // ---- weight transform: t = cin*64+cout over 2048 ----
    int t = bid * 256 + tid;
    if (t < 64) ws[OFF_CB + t] = conv_bias[t] + bias[t];
    if (t >= 32 * 64) return;
    const float s = 1.0f / 31.0f;
    const float* src = w + t * 27;               // (Cin, Cout, 3,3,3)
    float wv[27];
#pragma unroll
    for (int i = 0; i < 27; ++i) wv[i] = src[i] * s;
    float* dee = ws + OFF_EE + t * 3;
    float* deo = ws + OFF_EO + t * 6;
    float* doe = ws + OFF_OE + t * 6;
    float* doo = ws + OFF_OO + t * 12;
#pragma unroll
    for (int kd = 0; kd < 3; ++kd) {
      dee[kd]         = wv[kd * 9 + 4];          // (kh=1, kw=1)
      deo[kd * 2 + 0] = wv[kd * 9 + 3 + 0];      // (1,0) pairs iw0
      deo[kd * 2 + 1] = wv[kd * 9 + 3 + 2];      // (1,2) pairs iw1
      doe[kd * 2 + 0] = wv[kd * 9 + 0 + 1];      // (0,1) pairs ih0
      doe[kd * 2 + 1] = wv[kd * 9 + 6 + 1];      // (2,1) pairs ih1
      doo[kd * 4 + 0] = wv[kd * 9 + 0];          // (0,0)
      doo[kd * 4 + 1] = wv[kd * 9 + 2];          // (0,2)
      doo[kd * 4 + 2] = wv[kd * 9 + 6];          // (2,0)
      doo[kd * 4 + 3] = wv[kd * 9 + 8];          // (2,2)
    }
  } else {
    // ---- depth reduce, float4-vectorized: 65536 threads ----
    int t = (bid - 8) * 256 + tid;               // 0..65535
    int bc = t >> 8;                             // b*32+cin
    int c4 = t & 255;
    const float4* xp = (const float4*)x + (size_t)bc * 4096 + c4;
    float4 s0 = xp[0];
    float sx = s0.x, sy = s0.y, sz = s0.z, sw = s0.w;
#pragma unroll
    for (int d = 1; d < 15; ++d) {
      float4 v = xp[d * 256];
      sx += v.x; sy += v.y; sz += v.z; sw += v.w;
    }
    float4 s15 = xp[15 * 256];
    sx += s15.x; sy += s15.y; sz += s15.z; sw += s15.w;
    float4* Af = (float4*)(ws + OFF_A);
    float4 o;
    o.x = sx - s0.x;  o.y = sy - s0.y;  o.z = sz - s0.z;  o.w = sw - s0.w;
    Af[t] = o;                                   // A0
    o.x = sx; o.y = sy; o.z = sz; o.w = sw;
    Af[PLANE / 4 + t] = o;                       // A1
    o.x = sx - s15.x; o.y = sy - s15.y; o.z = sz - s15.z; o.w = sw - s15.w;
    Af[2 * (PLANE / 4) + t] = o;                 // A2
  }
}

// ---------------- main ----------------
template <int NH, int NW>
__device__ __forceinline__ void accum_f(const float* __restrict__ A,
                                        const float* __restrict__ wt,
                                        int b, int cin0, int ih0, int ih1,
                                        int iw0, int iw1, float acc[32]) {
  constexpr int T = 3 * NH * NW;
  for (int ci = 0; ci < 8; ++ci) {
    const int cin = cin0 + ci;
    const float* ap = A + (size_t)(b * 32 + cin) * 1024;
    float av[T];
#pragma unroll
    for (int kd = 0; kd < 3; ++kd) {
#pragma unroll
      for (int hi = 0; hi < NH; ++hi) {
        int ih = hi ? ih1 : ih0;
#pragma unroll
        for (int wi = 0; wi < NW; ++wi) {
          int iw = wi ? iw1 : iw0;
          av[(kd * NH + hi) * NW + wi] = ap[kd * PLANE + ih * 32 + iw];
        }
      }
    }
    const float* wr = wt + (size_t)cin * 64 * T;  // wave-uniform -> s_load
#pragma unroll
    for (int co = 0; co < 32; ++co) {
#pragma unroll
      for (int tt = 0; tt < T; ++tt)
        acc[co] = fmaf(wr[co * T + tt], av[tt], acc[co]);
    }
  }
}

extern "C" __global__ __launch_bounds__(512, 4) void k_main(
    const float* __restrict__ ws, float* __restrict__ out) {
  const int bid = blockIdx.x;                    // 512 blocks
  const int b  = bid >> 6;
  const int r  = bid & 63;
  const int rp = (r >> 5) & 1;                   // row parity
  const int k  = (r >> 1) & 15;                  // row-pair id
  const int cp = r & 1;                          // col parity
  const int tid = threadIdx.x;
  const int wid = __builtin_amdgcn_readfirstlane(tid >> 6);  // 0..7
  const int cinq = wid >> 1;                     // cin quarter
  const int ch   = wid & 1;                      // cout half (wave-uniform)
  const int lane = tid & 63;
  const int rr = lane >> 5, cc = lane & 31;
  const int oh = 4 * k + rp + 2 * rr;
  const int ow = 2 * cc + cp;
  const bool valid = (oh < 63) && (ow < 63);

  int ih0, ih1 = 0, iw0, iw1 = 0;
  if (rp) { int ia = (oh + 1) >> 1; ih0 = ia > 31 ? 31 : ia; ih1 = (oh - 1) >> 1; }
  else    { ih0 = oh >> 1; }
  if (cp) { int ja = cc + 1; iw0 = ja > 31 ? 31 : ja; iw1 = cc; }
  else    { iw0 = cc; }

  float acc[32];
#pragma unroll
  for (int i = 0; i < 32; ++i) acc[i] = 0.0f;

  const float* A = ws + OFF_A;
  const int cin0 = cinq * 8;
  const int par = rp * 2 + cp;
  if      (par == 0) accum_f<1, 1>(A, ws + OFF_EE + ch * 32 * 3,  b, cin0, ih0, ih1, iw0, iw1, acc);
  else if (par == 1) accum_f<1, 2>(A, ws + OFF_EO + ch * 32 * 6,  b, cin0, ih0, ih1, iw0, iw1, acc);
  else if (par == 2) accum_f<2, 1>(A, ws + OFF_OE + ch * 32 * 6,  b, cin0, ih0, ih1, iw0, iw1, acc);
  else               accum_f<2, 2>(A, ws + OFF_OO + ch * 32 * 12, b, cin0, ih0, ih1, iw0, iw1, acc);

  // cin reduce: waves 2..7 dump partials; waves 0 (ch=0) and 1 (ch=1) finish.
  __shared__ float part[6 * 64 * 33];            // 50.7 KB, stride 33 conflict-free
  __shared__ float exm[128];
  __shared__ float exs[128];
  if (wid >= 2) {
    float* row = &part[((wid - 2) * 64 + lane) * 33];
#pragma unroll
    for (int c = 0; c < 32; ++c) row[c] = acc[c];
  }
  __syncthreads();

  if (wid < 2) {
    const float* cb = ws + OFF_CB + ch * 32;
    float mx = -3.0e38f;
#pragma unroll
    for (int c = 0; c < 32; ++c) {
      acc[c] += part[((ch + 0) * 64 + lane) * 33 + c] +
                part[((ch + 2) * 64 + lane) * 33 + c] +
                part[((ch + 4) * 64 + lane) * 33 + c] + cb[c];
      mx = fmaxf(mx, acc[c]);
    }
    exm[lane * 2 + ch] = mx;
  }
  __syncthreads();

  if (wid < 2) {
    float m = fmaxf(exm[lane * 2], exm[lane * 2 + 1]);
    float sum = 0.0f;
#pragma unroll
    for (int c = 0; c < 32; ++c) {
      float e = __expf(acc[c] - m);
      acc[c] = e;
      sum += e;
    }
    exs[lane * 2 + ch] = sum;
  }
  __syncthreads();

  if (wid < 2 && valid) {
    float rs = 1.0f / (exs[lane * 2] + exs[lane * 2 + 1]);
    float* op = out + ((size_t)b * 64 + ch * 32) * 3969 + (size_t)oh * 63 + ow;
#pragma unroll
    for (int c = 0; c < 32; ++c) {
      float s = acc[c] * rs;
      float e2 = __expf(2.0f * s);               // 2*tanh(s) = 2 - 4/(e^{2s}+1)
      op[(size_t)c * 3969] = 2.0f - 4.0f / (e2 + 1.0f);
    }
  }
}

extern "C" void kernel_launch(void* const* d_in, const int* in_sizes, int n_in,
                              void* d_out, int out_size, void* d_ws,
                              size_t ws_size, hipStream_t stream) {
  const float* x  = (const float*)d_in[0];
  const float* w  = (const float*)d_in[1];
  const float* cb = (const float*)d_in[2];
  const float* bs = (const float*)d_in[3];
  float* ws  = (float*)d_ws;
  float* out = (float*)d_out;

  hipLaunchKernelGGL(k_prep, dim3(264), dim3(256), 0, stream, x, w, cb, bs, ws);
  hipLaunchKernelGGL(k_main, dim3(512), dim3(512), 0, stream, ws, out);
}

// Round 3
// 107.788 us; speedup vs baseline: 1.6380x; 1.0223x over previous
//
#include <hip/hip_runtime.h>
#include <cstddef>

// B=8, Cin=32, D=16, H=W=32 -> ConvTranspose3d(32->64, k=3, s=2, p=1)
// -> mean over depth (D'=31) -> +bias -> softmax over C=64 -> tanh*2.
// Output (8, 64, 1, 63, 63) fp32.
//
// Depth-mean folds into weights: A0 = S - x[0], A1 = S, A2 = S - x[15]
// (S = sum over d), m = cb + sum_kd Tconv2d(A_kd, w/31).
// Parity classes (oh&1, ow&1): taps/cin = 3 (EE), 6 (EO/OE), 12 (OO).
//
// k_main role assignment (the round-3 change): lanes = couts, so weights are
// per-lane VGPR-resident (loaded once, <=48 VGPR); A rows are wave-uniform
// -> s_load_dwordx16 of contiguous 32-float rows, each feeding 32-124 FMAs
// (v_fmac acc, s_a, v_w). Pixels live in acc[<=32]. Block = (b, oh, owpar).

namespace {
constexpr int PLANE  = 8 * 32 * 32 * 32;          // floats per A plane
constexpr int OFF_EE = 0;                          // T=3
constexpr int OFF_EO = 32 * 64 * 3;                // T=6
constexpr int OFF_OE = OFF_EO + 32 * 64 * 6;       // T=6
constexpr int OFF_OO = OFF_OE + 32 * 64 * 6;       // T=12
constexpr int OFF_CB = OFF_OO + 32 * 64 * 12;      // cb[64]
constexpr int OFF_A  = OFF_CB + 64;                // 3 planes follow
}

// ---------------- prep: weight transform (+bias) AND depth reduce ----------
extern "C" __global__ __launch_bounds__(256) void k_prep(
    const float* __restrict__ x, const float* __restrict__ w,
    const float* __restrict__ conv_bias, const float* __restrict__ bias,
    float* __restrict__ ws) {
  const int bid = blockIdx.x;
  const int tid = threadIdx.x;
  if (bid < 8) {
    // ---- weight transform: t = cin*64+cout over 2048 ----
    int t = bid * 256 + tid;
    if (t < 64) ws[OFF_CB + t] = conv_bias[t] + bias[t];
    if (t >= 32 * 64) return;
    const float s = 1.0f / 31.0f;
    const float* src = w + t * 27;                // (Cin, Cout, 3,3,3)
    float wv[27];
#pragma unroll
    for (int i = 0; i < 27; ++i) wv[i] = src[i] * s;
    float* dee = ws + OFF_EE + t * 3;
    float* deo = ws + OFF_EO + t * 6;
    float* doe = ws + OFF_OE + t * 6;
    float* doo = ws + OFF_OO + t * 12;
#pragma unroll
    for (int kd = 0; kd < 3; ++kd) {
      dee[kd]         = wv[kd * 9 + 4];           // (kh=1, kw=1)
      deo[kd * 2 + 0] = wv[kd * 9 + 3 + 0];       // (1,0) uses a[p+1]
      deo[kd * 2 + 1] = wv[kd * 9 + 3 + 2];       // (1,2) uses a[p]
      doe[kd * 2 + 0] = wv[kd * 9 + 0 + 1];       // (0,1) uses rowA=(oh+1)/2
      doe[kd * 2 + 1] = wv[kd * 9 + 6 + 1];       // (2,1) uses rowB=(oh-1)/2
      doo[kd * 4 + 0] = wv[kd * 9 + 0];           // (0,0) rowA, a[p+1]
      doo[kd * 4 + 1] = wv[kd * 9 + 2];           // (0,2) rowA, a[p]
      doo[kd * 4 + 2] = wv[kd * 9 + 6];           // (2,0) rowB, a[p+1]
      doo[kd * 4 + 3] = wv[kd * 9 + 8];           // (2,2) rowB, a[p]
    }
  } else {
    // ---- depth reduce, d-split across lane halves: 131072 threads ----
    int t = (bid - 8) * 256 + tid;                // 0..131071
    int g = t >> 6;                               // global wave id
    int lane = t & 63;
    int dh = lane >> 5;                           // depth half
    int o = g * 32 + (lane & 31);                 // float4 output index
    int bc = o >> 8;                              // b*32+cin
    int c4 = o & 255;
    const float4* xp = (const float4*)x + (size_t)bc * 4096 + c4;
    float4 vv[8];
#pragma unroll
    for (int j = 0; j < 8; ++j) vv[j] = xp[(dh * 8 + j) * 256];
    float sx = 0.f, sy = 0.f, sz = 0.f, sw = 0.f;
#pragma unroll
    for (int j = 0; j < 8; ++j) { sx += vv[j].x; sy += vv[j].y; sz += vv[j].z; sw += vv[j].w; }
    float fx = sx + __shfl_xor(sx, 32);
    float fy = sy + __shfl_xor(sy, 32);
    float fz = sz + __shfl_xor(sz, 32);
    float fw = sw + __shfl_xor(sw, 32);
    float4* Af = (float4*)(ws + OFF_A);
    if (dh == 0) {
      float4 a0; a0.x = fx - vv[0].x; a0.y = fy - vv[0].y; a0.z = fz - vv[0].z; a0.w = fw - vv[0].w;
      Af[o] = a0;                                  // A0 (drops d=0)
      float4 a1; a1.x = fx; a1.y = fy; a1.z = fz; a1.w = fw;
      Af[PLANE / 4 + o] = a1;                      // A1
    } else {
      float4 a2; a2.x = fx - vv[7].x; a2.y = fy - vv[7].y; a2.z = fz - vv[7].z; a2.w = fw - vv[7].w;
      Af[2 * (PLANE / 4) + o] = a2;                // A2 (drops d=15)
    }
  }
}

// ---------------- main ----------------
template <int RP, int CP>
__device__ __forceinline__ void conv_body(const float* __restrict__ ws,
                                          float* __restrict__ out,
                                          int b, int oh,
                                          float (*red)[64][33]) {
  constexpr int T  = 3 * (RP + 1) * (CP + 1);
  constexpr int NP = CP ? 31 : 32;
  constexpr int toff = RP ? (CP ? OFF_OO : OFF_OE) : (CP ? OFF_EO : OFF_EE);
  const int tid  = threadIdx.x;
  const int wid  = __builtin_amdgcn_readfirstlane(tid >> 6);  // 0..7
  const int lane = tid & 63;                       // cout
  const int cin0 = wid << 2;                       // 4 cins per wave
  const int ihA = RP ? (oh + 1) >> 1 : oh >> 1;    // kh=0 row (or kh=1 if RP=0)
  const int ihB = RP ? (oh - 1) >> 1 : 0;          // kh=2 row (RP only)

  // per-lane weights, loaded once (contiguous per cout -> dwordx4-ish)
  float wreg[4 * T];
  {
    const float* wt = ws + toff;
#pragma unroll
    for (int ci = 0; ci < 4; ++ci) {
      const float* wp = wt + (size_t)((cin0 + ci) * 64 + lane) * T;
#pragma unroll
      for (int tt = 0; tt < T; ++tt) wreg[ci * T + tt] = wp[tt];
    }
  }

  float acc[NP];
#pragma unroll
  for (int p = 0; p < NP; ++p) acc[p] = 0.0f;

  const float* A = ws + OFF_A;
#pragma unroll
  for (int ci = 0; ci < 4; ++ci) {
    const int rowbase = (b * 32 + cin0 + ci) * 32;
#pragma unroll
    for (int kd = 0; kd < 3; ++kd) {
      const float* arA = A + kd * PLANE + (rowbase + ihA) * 32;  // uniform -> s_load
      const float* arB = A + kd * PLANE + (rowbase + ihB) * 32;
      if constexpr (RP == 0 && CP == 0) {
        const float w0 = wreg[ci * 3 + kd];
#pragma unroll
        for (int p = 0; p < 32; ++p) acc[p] = fmaf(arA[p], w0, acc[p]);
      } else if constexpr (RP == 0 && CP == 1) {
        const float w0 = wreg[ci * 6 + kd * 2 + 0];
        const float w2 = wreg[ci * 6 + kd * 2 + 1];
#pragma unroll
        for (int p = 0; p < 31; ++p) {
          acc[p] = fmaf(arA[p + 1], w0, acc[p]);
          acc[p] = fmaf(arA[p],     w2, acc[p]);
        }
      } else if constexpr (RP == 1 && CP == 0) {
        const float wa = wreg[ci * 6 + kd * 2 + 0];
        const float wb = wreg[ci * 6 + kd * 2 + 1];
#pragma unroll
        for (int p = 0; p < 32; ++p) {
          acc[p] = fmaf(arA[p], wa, acc[p]);
          acc[p] = fmaf(arB[p], wb, acc[p]);
        }
      } else {
        const float w00 = wreg[ci * 12 + kd * 4 + 0];
        const float w02 = wreg[ci * 12 + kd * 4 + 1];
        const float w20 = wreg[ci * 12 + kd * 4 + 2];
        const float w22 = wreg[ci * 12 + kd * 4 + 3];
#pragma unroll
        for (int p = 0; p < 31; ++p) {
          acc[p] = fmaf(arA[p + 1], w00, acc[p]);
          acc[p] = fmaf(arA[p],     w02, acc[p]);
          acc[p] = fmaf(arB[p + 1], w20, acc[p]);
          acc[p] = fmaf(arB[p],     w22, acc[p]);
        }
      }
    }
  }

  // ---- cin tree-reduce (3 barriers, waves write their own just-read slot) --
  if (wid >= 4) {
#pragma unroll
    for (int p = 0; p < NP; ++p) red[wid - 4][lane][p] = acc[p];
  }
  __syncthreads();
  if (wid < 4) {
#pragma unroll
    for (int p = 0; p < NP; ++p) acc[p] += red[wid][lane][p];
  }
  if (wid == 2 || wid == 3) {
#pragma unroll
    for (int p = 0; p < NP; ++p) red[wid][lane][p] = acc[p];
  }
  __syncthreads();
  if (wid < 2) {
#pragma unroll
    for (int p = 0; p < NP; ++p) acc[p] += red[wid + 2][lane][p];
  }
  if (wid == 1) {
#pragma unroll
    for (int p = 0; p < NP; ++p) red[3][lane][p] = acc[p];
  }
  __syncthreads();
  if (wid == 0) {
    const float cbv = ws[OFF_CB + lane];
#pragma unroll
    for (int p = 0; p < NP; ++p)
      red[0][lane][p] = acc[p] + red[3][lane][p] + cbv;   // final m
  }
  __syncthreads();

  // ---- distributed softmax over couts (=lanes) + tanh + store -------------
#pragma unroll
  for (int k = 0; k < 4; ++k) {
    const int pix = wid * 4 + k;                  // uniform per wave
    float v = red[0][lane][pix < NP ? pix : 0];
    float mx = v;
#pragma unroll
    for (int m = 1; m < 64; m <<= 1) mx = fmaxf(mx, __shfl_xor(mx, m));
    float e = __expf(v - mx);
    float s = e;
#pragma unroll
    for (int m = 1; m < 64; m <<= 1) s += __shfl_xor(s, m);
    if (pix < NP) {
      float sv = e / s;
      float e2 = __expf(2.0f * sv);               // 2*tanh(s) = 2 - 4/(e^2s+1)
      float y = 2.0f - 4.0f / (e2 + 1.0f);
      const int ow = 2 * pix + CP;
      out[(((size_t)b * 64 + lane) * 63 + oh) * 63 + ow] = y;
    }
  }
}

extern "C" __global__ __launch_bounds__(512, 4) void k_main(
    const float* __restrict__ ws, float* __restrict__ out) {
  __shared__ float red[4][64][33];                 // 33.8 KB, shared by variants
  const int b  = blockIdx.y;
  const int rr = blockIdx.x;                       // 0..125
  const int oh = rr >> 1;
  const int cp = rr & 1;
  const int rp = oh & 1;
  if      (rp == 0 && cp == 0) conv_body<0, 0>(ws, out, b, oh, red);
  else if (rp == 0 && cp == 1) conv_body<0, 1>(ws, out, b, oh, red);
  else if (rp == 1 && cp == 0) conv_body<1, 0>(ws, out, b, oh, red);
  else                         conv_body<1, 1>(ws, out, b, oh, red);
}

extern "C" void kernel_launch(void* const* d_in, const int* in_sizes, int n_in,
                              void* d_out, int out_size, void* d_ws,
                              size_t ws_size, hipStream_t stream) {
  const float* x  = (const float*)d_in[0];
  const float* w  = (const float*)d_in[1];
  const float* cb = (const float*)d_in[2];
  const float* bs = (const float*)d_in[3];
  float* ws  = (float*)d_ws;
  float* out = (float*)d_out;

  hipLaunchKernelGGL(k_prep, dim3(520), dim3(256), 0, stream, x, w, cb, bs, ws);
  hipLaunchKernelGGL(k_main, dim3(126, 8), dim3(512), 0, stream, ws, out);
}